// Round 1
// baseline (798.504 us; speedup 1.0000x reference)
//
#include <hip/hip_runtime.h>
#include <math.h>

#define B_   4
#define CIN_ 64
#define COUT_ 64
#define H_   128
#define W_   160
#define HW_  (H_*W_)
#define NPIX_ (B_*HW_)
#define CMI_ 72
#define CMO_ 27
#define EPS_ 1e-8f

// ---------------------------------------------------------------------------
// Kernel 1: cosine similarity of each pixel's channel vector vs its 8
// neighbors (zero-padded). sim layout: [B][8][H][W]
// ---------------------------------------------------------------------------
__global__ __launch_bounds__(256) void sim_kernel(const float* __restrict__ x,
                                                  float* __restrict__ sim)
{
    const int pix = blockIdx.x * 256 + threadIdx.x;   // grid sized exactly
    const int w = pix % W_;
    const int h = (pix / W_) % H_;
    const int b = pix / HW_;
    const int p0 = h * W_ + w;
    const float* xb = x + (size_t)b * CIN_ * HW_;

    const int kyA[8] = {-1,-1,-1, 0, 0, 1, 1, 1};
    const int kxA[8] = {-1, 0, 1,-1, 1,-1, 0, 1};
    int   offn[8];
    float mskn[8];
#pragma unroll
    for (int n = 0; n < 8; n++) {
        int hh = h + kyA[n], ww = w + kxA[n];
        bool v = (hh >= 0) & (hh < H_) & (ww >= 0) & (ww < W_);
        int hc = min(max(hh, 0), H_-1), wc = min(max(ww, 0), W_-1);
        offn[n] = hc * W_ + wc;
        mskn[n] = v ? 1.f : 0.f;
    }

    float dot[8], nn[8], ncc = 0.f;
#pragma unroll
    for (int n = 0; n < 8; n++) { dot[n] = 0.f; nn[n] = 0.f; }

    for (int c = 0; c < CIN_; c++) {
        const float* xc = xb + c * HW_;
        float cv = xc[p0];
        ncc = fmaf(cv, cv, ncc);
#pragma unroll
        for (int n = 0; n < 8; n++) {
            float v = xc[offn[n]] * mskn[n];
            dot[n] = fmaf(cv, v, dot[n]);
            nn[n]  = fmaf(v, v, nn[n]);
        }
    }
    float nc = fmaxf(sqrtf(ncc), EPS_);
#pragma unroll
    for (int n = 0; n < 8; n++) {
        float nk = fmaxf(sqrtf(nn[n]), EPS_);
        sim[((size_t)b * 8 + n) * HW_ + p0] = dot[n] / (nc * nk);
    }
}

// ---------------------------------------------------------------------------
// Kernel 2: 3x3 conv, input = concat([x(64), sim(8)]) -> om (27 ch) + bias.
// Weights staged to dynamic LDS as [cin][tap][cout] (17496 floats = 68 KB).
// ---------------------------------------------------------------------------
__global__ __launch_bounds__(256) void cm_conv_kernel(const float* __restrict__ x,
                                                      const float* __restrict__ sim,
                                                      const float* __restrict__ cmw,
                                                      const float* __restrict__ cmb,
                                                      float* __restrict__ om)
{
    extern __shared__ float wlds[];                   // [CMI_][9][CMO_]
    for (int i = threadIdx.x; i < CMI_ * 9 * CMO_; i += 256) {
        int c = i / (9 * CMO_);
        int r = i - c * 9 * CMO_;
        int t = r / CMO_;
        int o = r - t * CMO_;
        wlds[i] = cmw[((size_t)o * CMI_ + c) * 9 + t];
    }
    __syncthreads();

    const int pix = blockIdx.x * 256 + threadIdx.x;
    const int w = pix % W_;
    const int h = (pix / W_) % H_;
    const int b = pix / HW_;
    const int p0 = h * W_ + w;

    int   offt[9];
    float mskt[9];
#pragma unroll
    for (int t = 0; t < 9; t++) {
        int hh = h + t / 3 - 1, ww = w + t % 3 - 1;
        bool v = (hh >= 0) & (hh < H_) & (ww >= 0) & (ww < W_);
        offt[t] = min(max(hh, 0), H_-1) * W_ + min(max(ww, 0), W_-1);
        mskt[t] = v ? 1.f : 0.f;
    }

    float acc[CMO_];
#pragma unroll
    for (int o = 0; o < CMO_; o++) acc[o] = 0.f;

    const float* xb = x   + (size_t)b * CIN_ * HW_;
    const float* sb = sim + (size_t)b * 8 * HW_;
    for (int cin = 0; cin < CMI_; cin++) {
        const float* src = (cin < CIN_) ? (xb + cin * HW_) : (sb + (cin - CIN_) * HW_);
        const float* wl0 = &wlds[cin * 9 * CMO_];
#pragma unroll
        for (int t = 0; t < 9; t++) {
            float v = src[offt[t]] * mskt[t];
            const float* wl = wl0 + t * CMO_;
#pragma unroll
            for (int o = 0; o < CMO_; o++) acc[o] = fmaf(v, wl[o], acc[o]);
        }
    }
#pragma unroll
    for (int o = 0; o < CMO_; o++)
        om[((size_t)b * CMO_ + o) * HW_ + p0] = acc[o] + cmb[o];
}

// ---------------------------------------------------------------------------
// Kernel 3: modulated deformable conv. om channels: [0..17]=offset (dy,dx
// interleaved per k), [18..26]=mask logits. Weights LDS-staged per k-chunk
// of 3: [c][kk][o] = 64*3*64 floats = 48 KB.
// ---------------------------------------------------------------------------
__global__ __launch_bounds__(256) void dcn_kernel(const float* __restrict__ x,
                                                  const float* __restrict__ om,
                                                  const float* __restrict__ wt,
                                                  const float* __restrict__ bias,
                                                  float* __restrict__ out)
{
    __shared__ float wlds[CIN_ * 3 * COUT_];          // 48 KB
    const int pix = blockIdx.x * 256 + threadIdx.x;
    const int w = pix % W_;
    const int h = (pix / W_) % H_;
    const int b = pix / HW_;
    const int p0 = h * W_ + w;
    const float* xb  = x  + (size_t)b * CIN_ * HW_;
    const float* omb = om + (size_t)b * CMO_ * HW_;

    float acc[COUT_];
#pragma unroll
    for (int o = 0; o < COUT_; o++) acc[o] = 0.f;

    for (int kc = 0; kc < 3; kc++) {
        __syncthreads();
        for (int i = threadIdx.x; i < CIN_ * 3 * COUT_; i += 256) {
            int o  = i & 63;
            int r  = i >> 6;
            int kk = r % 3;
            int c  = r / 3;
            wlds[i] = wt[((size_t)o * CIN_ + c) * 9 + kc * 3 + kk];
        }
        __syncthreads();

#pragma unroll
        for (int kk = 0; kk < 3; kk++) {
            const int k = kc * 3 + kk;
            float dy = omb[(2 * k) * HW_ + p0];
            float dx = omb[(2 * k + 1) * HW_ + p0];
            float mz = omb[(18 + k) * HW_ + p0];
            float m  = 1.f / (1.f + expf(-mz));

            float py = (float)(h + k / 3 - 1) + dy;
            float px = (float)(w + k % 3 - 1) + dx;
            float y0f = floorf(py), x0f = floorf(px);
            int y0 = (int)y0f, x0 = (int)x0f;
            float wy = py - y0f, wx = px - x0f;

            bool vy0 = (y0 >= 0)     & (y0 < H_);
            bool vy1 = (y0 + 1 >= 0) & (y0 + 1 < H_);
            bool vx0 = (x0 >= 0)     & (x0 < W_);
            bool vx1 = (x0 + 1 >= 0) & (x0 + 1 < W_);
            float w00 = (1.f - wy) * (1.f - wx) * m * ((vy0 & vx0) ? 1.f : 0.f);
            float w01 = (1.f - wy) * wx         * m * ((vy0 & vx1) ? 1.f : 0.f);
            float w10 = wy * (1.f - wx)         * m * ((vy1 & vx0) ? 1.f : 0.f);
            float w11 = wy * wx                 * m * ((vy1 & vx1) ? 1.f : 0.f);

            int y0c = min(max(y0, 0), H_-1), y1c = min(max(y0 + 1, 0), H_-1);
            int x0c = min(max(x0, 0), W_-1), x1c = min(max(x0 + 1, 0), W_-1);
            int o00 = y0c * W_ + x0c, o01 = y0c * W_ + x1c;
            int o10 = y1c * W_ + x0c, o11 = y1c * W_ + x1c;

            for (int c = 0; c < CIN_; c++) {
                const float* xc = xb + c * HW_;
                float v = w00 * xc[o00] + w01 * xc[o01]
                        + w10 * xc[o10] + w11 * xc[o11];
                const float* wl = &wlds[(c * 3 + kk) * COUT_];
#pragma unroll
                for (int o = 0; o < COUT_; o++) acc[o] = fmaf(v, wl[o], acc[o]);
            }
        }
    }
#pragma unroll
    for (int o = 0; o < COUT_; o++)
        out[((size_t)b * COUT_ + o) * HW_ + p0] = acc[o] + bias[o];
}

// ---------------------------------------------------------------------------
extern "C" void kernel_launch(void* const* d_in, const int* in_sizes, int n_in,
                              void* d_out, int out_size, void* d_ws, size_t ws_size,
                              hipStream_t stream)
{
    const float* x   = (const float*)d_in[0];
    const float* wt  = (const float*)d_in[1];
    const float* bs  = (const float*)d_in[2];
    const float* cmw = (const float*)d_in[3];
    const float* cmb = (const float*)d_in[4];
    float* out = (float*)d_out;

    float* sim = (float*)d_ws;                        // B*8*HW floats
    float* om  = sim + (size_t)B_ * 8 * HW_;          // B*27*HW floats

    const int nblk = NPIX_ / 256;                     // 320, exact
    sim_kernel<<<nblk, 256, 0, stream>>>(x, sim);
    cm_conv_kernel<<<nblk, 256, CMI_ * 9 * CMO_ * sizeof(float), stream>>>(x, sim, cmw, cmb, om);
    dcn_kernel<<<nblk, 256, 0, stream>>>(x, om, wt, bs, out);
}

// Round 2
// 330.157 us; speedup vs baseline: 2.4186x; 2.4186x over previous
//
#include <hip/hip_runtime.h>
#include <math.h>

#define B_    4
#define CIN_  64
#define COUT_ 64
#define H_    128
#define W_    160
#define HW_   (H_*W_)
#define NPIX_ (B_*HW_)      // 81920
#define XC_   72            // NHWC channel stride: x(64) + sim(8)
#define OMC_  28            // om channels padded (27 used)
#define EPS_  1e-8f

typedef float f4 __attribute__((ext_vector_type(4)));

// ---------------------------------------------------------------------------
// prep: transpose both weight tensors into GEMM-friendly layouts.
// wdT[k][c][o]  (9*64*64)   from weight[o][c][k]
// cwT[c][t][o28](72*9*28)   from cm_weight[o][c][t], padded to 28 couts
// ---------------------------------------------------------------------------
__global__ __launch_bounds__(256) void prep_kernel(const float* __restrict__ wt,
                                                   const float* __restrict__ cmw,
                                                   float* __restrict__ wdT,
                                                   float* __restrict__ cwT)
{
    int i = blockIdx.x * 256 + threadIdx.x;
    if (i < 9*64*64) {
        int k = i >> 12, r = i & 4095, c = r >> 6, o = r & 63;
        wdT[i] = wt[(o*64 + c)*9 + k];
    }
    int j = i - 9*64*64;
    if (j >= 0 && j < 72*9*28) {
        int c = j / 252, r = j % 252, t = r / 28, o = r % 28;
        cwT[j] = (o < 27) ? cmw[(o*72 + c)*9 + t] : 0.f;
    }
}

// ---------------------------------------------------------------------------
// xpose: NCHW x -> NHWC xs[px][0..63]  (channels 64..71 filled by sim_kernel)
// ---------------------------------------------------------------------------
__global__ __launch_bounds__(128) void xpose_kernel(const float* __restrict__ x,
                                                    float* __restrict__ xs)
{
    __shared__ float l[128][65];                    // 65: conflict-free fill
    const int t = threadIdx.x;
    const int px0 = blockIdx.x * 128;               // 128 px per block, no batch crossing
    const int b = px0 / HW_, p0 = px0 % HW_;
    for (int c = 0; c < 64; c++)
        l[t][c] = x[((size_t)(b*64 + c))*HW_ + p0 + t];
    __syncthreads();
#pragma unroll
    for (int rep = 0; rep < 16; rep++) {
        int pxl = (t >> 4) + rep*8;
        int c4  = (t & 15) * 4;
        f4 v = { l[pxl][c4], l[pxl][c4+1], l[pxl][c4+2], l[pxl][c4+3] };
        *reinterpret_cast<f4*>(&xs[(size_t)(px0+pxl)*XC_ + c4]) = v;
    }
}

// ---------------------------------------------------------------------------
// sim: per-pixel cosine similarity vs 8 neighbors, vectorized NHWC reads.
// Writes xs[px][64+n].
// ---------------------------------------------------------------------------
__global__ __launch_bounds__(256) void sim_kernel(float* __restrict__ xs)
{
    const int px = blockIdx.x * 256 + threadIdx.x;
    const int w = px % W_, h = (px / W_) % H_, b = px / HW_;

    const float* cen = xs + (size_t)px * XC_;
    f4 cv[16];
    float ncc = 0.f;
#pragma unroll
    for (int q = 0; q < 16; q++) {
        cv[q] = reinterpret_cast<const f4*>(cen)[q];
#pragma unroll
        for (int j = 0; j < 4; j++) ncc = fmaf(cv[q][j], cv[q][j], ncc);
    }
    const float ncr = 1.f / fmaxf(sqrtf(ncc), EPS_);

    const int kyA[8] = {-1,-1,-1, 0, 0, 1, 1, 1};
    const int kxA[8] = {-1, 0, 1,-1, 1,-1, 0, 1};
    float res[8];
#pragma unroll
    for (int n = 0; n < 8; n++) {
        int hh = h + kyA[n], ww = w + kxA[n];
        bool v = (hh >= 0) & (hh < H_) & (ww >= 0) & (ww < W_);
        float msk = v ? 1.f : 0.f;
        const float* nb = xs + (size_t)(b*HW_ + min(max(hh,0),H_-1)*W_ + min(max(ww,0),W_-1)) * XC_;
        float dot = 0.f, nn = 0.f;
#pragma unroll
        for (int q = 0; q < 16; q++) {
            f4 qv = reinterpret_cast<const f4*>(nb)[q];
#pragma unroll
            for (int j = 0; j < 4; j++) {
                float vv = qv[j] * msk;
                dot = fmaf(cv[q][j], vv, dot);
                nn  = fmaf(vv, vv, nn);
            }
        }
        res[n] = dot * ncr / fmaxf(sqrtf(nn), EPS_);
    }
    float* sp = xs + (size_t)px * XC_ + 64;
#pragma unroll
    for (int n = 0; n < 8; n++) sp[n] = res[n];
}

// ---------------------------------------------------------------------------
// cm: 3x3 conv 72->27(+pad). Weight indices are thread-independent ->
// compiler scalarizes to s_load; FMA = v_fmac(vgpr, sgpr, vgpr).
// om NHWC [px][28].
// ---------------------------------------------------------------------------
__global__ __launch_bounds__(256) void cm_kernel(const float* __restrict__ xs,
                                                 const float* __restrict__ cwT,
                                                 const float* __restrict__ cmb,
                                                 float* __restrict__ om)
{
    const int px = blockIdx.x * 256 + threadIdx.x;
    const int w = px % W_, h = (px / W_) % H_, b = px / HW_;

    float acc[28];
#pragma unroll
    for (int o = 0; o < 28; o++) acc[o] = 0.f;

    for (int t = 0; t < 9; t++) {
        int hh = h + t/3 - 1, ww = w + t%3 - 1;
        bool vld = (hh >= 0) & (hh < H_) & (ww >= 0) & (ww < W_);
        float msk = vld ? 1.f : 0.f;
        const float* nb = xs + (size_t)(b*HW_ + min(max(hh,0),H_-1)*W_ + min(max(ww,0),W_-1)) * XC_;
#pragma unroll 2
        for (int c4 = 0; c4 < 18; c4++) {
            f4 xv = reinterpret_cast<const f4*>(nb)[c4];
#pragma unroll
            for (int j = 0; j < 4; j++) {
                float v = xv[j] * msk;
                const float* wr = &cwT[((c4*4 + j)*9 + t) * 28];
#pragma unroll
                for (int o = 0; o < 28; o++) acc[o] = fmaf(v, wr[o], acc[o]);
            }
        }
    }
    float* op = om + (size_t)px * OMC_;
#pragma unroll
    for (int o = 0; o < 27; o++) op[o] = acc[o] + cmb[o];
    op[27] = 0.f;
}

// ---------------------------------------------------------------------------
// dcn: tiled implicit GEMM. Block = 128 px x 64 couts, K = 9 taps x 64 c.
// Per k: stage bilinear val-tile vt[c][px] + weight tile wl[c][o] in LDS,
// then 64-deep FMA with 4px x 8o register tiles.
// ---------------------------------------------------------------------------
__global__ __launch_bounds__(256) void dcn_kernel(const float* __restrict__ xs,
                                                  const float* __restrict__ om,
                                                  const float* __restrict__ wdT,
                                                  const float* __restrict__ bias,
                                                  float* __restrict__ out)
{
    __shared__ float vt[64][132];                   // val^T: [c][px], pad 132
    __shared__ float wl[64][68];                    // weights: [c][o], pad 68

    const int t   = threadIdx.x;
    const int px0 = blockIdx.x * 128;               // 160 blocks/batch: no crossing
    // staging role: pixel pxl, channel-half
    const int pxl = t >> 1, half = t & 1;
    // gemm role: 4-px group, 8-cout group
    const int pxg = t >> 3, og = t & 7;

    const int pxs = px0 + pxl;
    const int wsx = pxs % W_, hs = (pxs / W_) % H_, bs = pxs / HW_;
    const float* omp = om + (size_t)pxs * OMC_;
    const size_t xrow = (size_t)bs * HW_;

    float acc[4][8];
#pragma unroll
    for (int i = 0; i < 4; i++)
#pragma unroll
        for (int j = 0; j < 8; j++) acc[i][j] = 0.f;

#pragma unroll 1
    for (int k = 0; k < 9; k++) {
        // ---- per-pixel bilinear setup (half-redundant, cheap) ----
        float dy = omp[2*k], dx = omp[2*k + 1], mz = omp[18 + k];
        float m  = 1.f / (1.f + __expf(-mz));
        float py = (float)(hs + k/3 - 1) + dy;
        float pxx= (float)(wsx + k%3 - 1) + dx;
        float y0f = floorf(py), x0f = floorf(pxx);
        int   y0 = (int)y0f,   x0 = (int)x0f;
        float wy = py - y0f,   wx = pxx - x0f;
        bool vy0 = (y0 >= 0)  & (y0 < H_);
        bool vy1 = (y0 >= -1) & (y0 < H_ - 1);
        bool vx0 = (x0 >= 0)  & (x0 < W_);
        bool vx1 = (x0 >= -1) & (x0 < W_ - 1);
        float w00 = (1.f-wy)*(1.f-wx)*m*((vy0&vx0)?1.f:0.f);
        float w01 = (1.f-wy)*wx      *m*((vy0&vx1)?1.f:0.f);
        float w10 = wy*(1.f-wx)      *m*((vy1&vx0)?1.f:0.f);
        float w11 = wy*wx            *m*((vy1&vx1)?1.f:0.f);
        int y0c = min(max(y0,   0), H_-1), y1c = min(max(y0+1, 0), H_-1);
        int x0c = min(max(x0,   0), W_-1), x1c = min(max(x0+1, 0), W_-1);
        const float* p00 = xs + (size_t)(xrow + y0c*W_ + x0c)*XC_ + half*32;
        const float* p01 = xs + (size_t)(xrow + y0c*W_ + x1c)*XC_ + half*32;
        const float* p10 = xs + (size_t)(xrow + y1c*W_ + x0c)*XC_ + half*32;
        const float* p11 = xs + (size_t)(xrow + y1c*W_ + x1c)*XC_ + half*32;

        float v[32];
#pragma unroll
        for (int q = 0; q < 8; q++) {
            f4 a = *reinterpret_cast<const f4*>(p00 + q*4);
            f4 bq= *reinterpret_cast<const f4*>(p01 + q*4);
            f4 c = *reinterpret_cast<const f4*>(p10 + q*4);
            f4 d = *reinterpret_cast<const f4*>(p11 + q*4);
#pragma unroll
            for (int j = 0; j < 4; j++)
                v[q*4+j] = w00*a[j] + w01*bq[j] + w10*c[j] + w11*d[j];
        }

        __syncthreads();                            // prev GEMM done before overwrite
#pragma unroll
        for (int j = 0; j < 32; j++) vt[half*32 + j][pxl] = v[j];
#pragma unroll
        for (int r = 0; r < 16; r++) {
            int i = r*256 + t;
            wl[i >> 6][i & 63] = wdT[k*4096 + i];
        }
        __syncthreads();

        // ---- GEMM: 64 c-steps, 3 ds_read_b128 + 32 FMA each ----
#pragma unroll 4
        for (int c = 0; c < 64; c++) {
            f4 v4 = *reinterpret_cast<const f4*>(&vt[c][pxg*4]);
            f4 wa = *reinterpret_cast<const f4*>(&wl[c][og*8]);
            f4 wb = *reinterpret_cast<const f4*>(&wl[c][og*8 + 4]);
#pragma unroll
            for (int i = 0; i < 4; i++) {
                acc[i][0] = fmaf(v4[i], wa[0], acc[i][0]);
                acc[i][1] = fmaf(v4[i], wa[1], acc[i][1]);
                acc[i][2] = fmaf(v4[i], wa[2], acc[i][2]);
                acc[i][3] = fmaf(v4[i], wa[3], acc[i][3]);
                acc[i][4] = fmaf(v4[i], wb[0], acc[i][4]);
                acc[i][5] = fmaf(v4[i], wb[1], acc[i][5]);
                acc[i][6] = fmaf(v4[i], wb[2], acc[i][6]);
                acc[i][7] = fmaf(v4[i], wb[3], acc[i][7]);
            }
        }
    }

    // ---- epilogue: NCHW output, float4 over the 4-px group ----
    const int bo = px0 / HW_, po = px0 % HW_;
#pragma unroll
    for (int j = 0; j < 8; j++) {
        int o = og*8 + j;
        float bv = bias[o];
        f4 r = { acc[0][j] + bv, acc[1][j] + bv, acc[2][j] + bv, acc[3][j] + bv };
        *reinterpret_cast<f4*>(&out[((size_t)(bo*64 + o))*HW_ + po + pxg*4]) = r;
    }
}

// ---------------------------------------------------------------------------
extern "C" void kernel_launch(void* const* d_in, const int* in_sizes, int n_in,
                              void* d_out, int out_size, void* d_ws, size_t ws_size,
                              hipStream_t stream)
{
    const float* x   = (const float*)d_in[0];
    const float* wt  = (const float*)d_in[1];
    const float* bs  = (const float*)d_in[2];
    const float* cmw = (const float*)d_in[3];
    const float* cmb = (const float*)d_in[4];
    float* out = (float*)d_out;

    float* xs  = (float*)d_ws;                      // NPIX_*72
    float* om  = xs  + (size_t)NPIX_ * XC_;         // NPIX_*28
    float* wdT = om  + (size_t)NPIX_ * OMC_;        // 9*64*64
    float* cwT = wdT + 9*64*64;                     // 72*9*28

    prep_kernel <<<215, 256, 0, stream>>>(wt, cmw, wdT, cwT);
    xpose_kernel<<<NPIX_/128, 128, 0, stream>>>(x, xs);
    sim_kernel  <<<NPIX_/256, 256, 0, stream>>>(xs);
    cm_kernel   <<<NPIX_/256, 256, 0, stream>>>(xs, cwT, cmb, om);
    dcn_kernel  <<<NPIX_/128, 256, 0, stream>>>(xs, om, wdT, bs, out);
}

// Round 3
// 292.378 us; speedup vs baseline: 2.7311x; 1.1292x over previous
//
#include <hip/hip_runtime.h>
#include <math.h>

#define B_    4
#define CIN_  64
#define COUT_ 64
#define H_    128
#define W_    160
#define HW_   (H_*W_)
#define NPIX_ (B_*HW_)      // 81920
#define XC_   72            // NHWC channel stride: x(64) + sim(8)
#define OMC_  28            // om channels padded (27 used)
#define EPS_  1e-8f

typedef float  f4    __attribute__((ext_vector_type(4)));
typedef float  f32x4 __attribute__((ext_vector_type(4)));
typedef short  bf16x8 __attribute__((ext_vector_type(8)));
typedef unsigned short ushort_t;

static __device__ __forceinline__ ushort_t f2bf(float f) {
    union { float f; unsigned u; } cv; cv.f = f;
    unsigned u = cv.u;
    return (ushort_t)((u + 0x7FFF + ((u >> 16) & 1)) >> 16);   // RNE
}

// ---------------------------------------------------------------------------
// prep:
//  wstage[k][g] bf16 (9*4096): pre-transposed + pre-SWIZZLED dcn weights so a
//    LINEAR 16B-chunk copy into LDS yields layout Wt[o][c] with
//    byte ^= ((o&7)<<4). Reader XORs the same -> gets Wt[o][c].
//  cwT[c][t][o28] f32: cm weights, padded to 28 couts.
// ---------------------------------------------------------------------------
__global__ __launch_bounds__(256) void prep_kernel(const float* __restrict__ wt,
                                                   const float* __restrict__ cmw,
                                                   short* __restrict__ wstage,
                                                   float* __restrict__ cwT)
{
    int i = blockIdx.x * 256 + threadIdx.x;
    if (i < 9*4096) {
        int k = i >> 12, g = i & 4095;
        int row = g >> 6;                                   // o
        int cc  = ((((g & 63) << 1) ^ ((row & 7) << 4)) >> 1);
        wstage[i] = (short)f2bf(wt[(row*64 + cc)*9 + k]);
    }
    int j = i - 9*4096;
    if (j >= 0 && j < 72*9*28) {
        int c = j / 252, r = j % 252, t = r / 28, o = r % 28;
        cwT[j] = (o < 27) ? cmw[(o*72 + c)*9 + t] : 0.f;
    }
}

// ---------------------------------------------------------------------------
// xpose: NCHW x -> NHWC xs[px][0..63]  (channels 64..71 filled by sim_kernel)
// ---------------------------------------------------------------------------
__global__ __launch_bounds__(128) void xpose_kernel(const float* __restrict__ x,
                                                    float* __restrict__ xs)
{
    __shared__ float l[128][65];
    const int t = threadIdx.x;
    const int px0 = blockIdx.x * 128;
    const int b = px0 / HW_, p0 = px0 % HW_;
    for (int c = 0; c < 64; c++)
        l[t][c] = x[((size_t)(b*64 + c))*HW_ + p0 + t];
    __syncthreads();
#pragma unroll
    for (int rep = 0; rep < 16; rep++) {
        int pxl = (t >> 4) + rep*8;
        int c4  = (t & 15) * 4;
        f4 v = { l[pxl][c4], l[pxl][c4+1], l[pxl][c4+2], l[pxl][c4+3] };
        *reinterpret_cast<f4*>(&xs[(size_t)(px0+pxl)*XC_ + c4]) = v;
    }
}

// ---------------------------------------------------------------------------
// sim: per-pixel cosine similarity vs 8 neighbors. Writes xs[px][64+n].
// ---------------------------------------------------------------------------
__global__ __launch_bounds__(256) void sim_kernel(float* __restrict__ xs)
{
    const int wg = blockIdx.x;
    const int sw = (wg & 7) * 40 + (wg >> 3);               // XCD-contiguous
    const int px = sw * 256 + threadIdx.x;
    const int w = px % W_, h = (px / W_) % H_, b = px / HW_;

    const float* cen = xs + (size_t)px * XC_;
    f4 cv[16];
    float ncc = 0.f;
#pragma unroll
    for (int q = 0; q < 16; q++) {
        cv[q] = reinterpret_cast<const f4*>(cen)[q];
#pragma unroll
        for (int j = 0; j < 4; j++) ncc = fmaf(cv[q][j], cv[q][j], ncc);
    }
    const float ncr = 1.f / fmaxf(sqrtf(ncc), EPS_);

    const int kyA[8] = {-1,-1,-1, 0, 0, 1, 1, 1};
    const int kxA[8] = {-1, 0, 1,-1, 1,-1, 0, 1};
    float res[8];
#pragma unroll
    for (int n = 0; n < 8; n++) {
        int hh = h + kyA[n], ww = w + kxA[n];
        bool v = (hh >= 0) & (hh < H_) & (ww >= 0) & (ww < W_);
        float msk = v ? 1.f : 0.f;
        const float* nb = xs + (size_t)(b*HW_ + min(max(hh,0),H_-1)*W_ + min(max(ww,0),W_-1)) * XC_;
        float dot = 0.f, nn = 0.f;
#pragma unroll
        for (int q = 0; q < 16; q++) {
            f4 qv = reinterpret_cast<const f4*>(nb)[q];
#pragma unroll
            for (int j = 0; j < 4; j++) {
                float vv = qv[j] * msk;
                dot = fmaf(cv[q][j], vv, dot);
                nn  = fmaf(vv, vv, nn);
            }
        }
        res[n] = dot * ncr / fmaxf(sqrtf(nn), EPS_);
    }
    float* sp = xs + (size_t)px * XC_ + 64;
#pragma unroll
    for (int n = 0; n < 8; n++) sp[n] = res[n];
}

// ---------------------------------------------------------------------------
// cm: 3x3 conv 72->27(+pad), f32 sgpr-weight FMA. om NHWC [px][28].
// ---------------------------------------------------------------------------
__global__ __launch_bounds__(256) void cm_kernel(const float* __restrict__ xs,
                                                 const float* __restrict__ cwT,
                                                 const float* __restrict__ cmb,
                                                 float* __restrict__ om)
{
    const int wg = blockIdx.x;
    const int sw = (wg & 7) * 40 + (wg >> 3);
    const int px = sw * 256 + threadIdx.x;
    const int w = px % W_, h = (px / W_) % H_, b = px / HW_;

    float acc[28];
#pragma unroll
    for (int o = 0; o < 28; o++) acc[o] = 0.f;

    for (int t = 0; t < 9; t++) {
        int hh = h + t/3 - 1, ww = w + t%3 - 1;
        bool vld = (hh >= 0) & (hh < H_) & (ww >= 0) & (ww < W_);
        float msk = vld ? 1.f : 0.f;
        const float* nb = xs + (size_t)(b*HW_ + min(max(hh,0),H_-1)*W_ + min(max(ww,0),W_-1)) * XC_;
#pragma unroll 2
        for (int c4 = 0; c4 < 18; c4++) {
            f4 xv = reinterpret_cast<const f4*>(nb)[c4];
#pragma unroll
            for (int j = 0; j < 4; j++) {
                float v = xv[j] * msk;
                const float* wr = &cwT[((c4*4 + j)*9 + t) * 28];
#pragma unroll
                for (int o = 0; o < 28; o++) acc[o] = fmaf(v, wr[o], acc[o]);
            }
        }
    }
    float* op = om + (size_t)px * OMC_;
#pragma unroll
    for (int o = 0; o < 27; o++) op[o] = acc[o] + cmb[o];
    op[27] = 0.f;
}

// ---------------------------------------------------------------------------
// dcn: bf16 MFMA implicit GEMM. Block = 128 px x 64 o, 4 waves (each 32px x 64o).
// Per tap: stage bilinear val tile [128px][64c] bf16 (XOR-swizzled) + weight
// tile Wt[o][c] (pre-swizzled linear copy), then 16 mfma_16x16x32 per wave.
// ---------------------------------------------------------------------------
__global__ __launch_bounds__(256) void dcn_kernel(const float* __restrict__ xs,
                                                  const float* __restrict__ om,
                                                  const short* __restrict__ wstage,
                                                  const float* __restrict__ bias,
                                                  float* __restrict__ out)
{
    __shared__ __align__(16) short As[128*64];              // 16 KB, row=px (128B)
    __shared__ __align__(16) short Ws[64*64];               // 8 KB,  row=o  (128B)

    const int t  = threadIdx.x;
    const int wg = blockIdx.x;
    const int sw = (wg & 7) * 80 + (wg >> 3);               // XCD-contiguous
    const int px0 = sw * 128;

    const int lane = t & 63, wv = t >> 6;
    const int fr = lane & 15, fq = lane >> 4;
    const int swz = (fr & 7) << 4;

    // staging role: pixel pxl, channel-half
    const int pxl = t >> 1, half = t & 1;
    const int pxs = px0 + pxl;
    const int wsx = pxs % W_, hs = (pxs / W_) % H_, bs = pxs / HW_;
    const float* omp = om + (size_t)pxs * OMC_;
    const size_t xrow = (size_t)bs * HW_;

    f32x4 acc[2][4];
#pragma unroll
    for (int i = 0; i < 2; i++)
#pragma unroll
        for (int j = 0; j < 4; j++) acc[i][j] = (f32x4){0.f,0.f,0.f,0.f};

#pragma unroll 1
    for (int k = 0; k < 9; k++) {
        // ---- bilinear val for 32 channels of pixel pxl ----
        float dy = omp[2*k], dx = omp[2*k + 1], mz = omp[18 + k];
        float m  = 1.f / (1.f + __expf(-mz));
        float py = (float)(hs + k/3 - 1) + dy;
        float pxx= (float)(wsx + k%3 - 1) + dx;
        float y0f = floorf(py), x0f = floorf(pxx);
        int   y0 = (int)y0f,   x0 = (int)x0f;
        float wy = py - y0f,   wx = pxx - x0f;
        bool vy0 = (y0 >= 0)  & (y0 < H_);
        bool vy1 = (y0 >= -1) & (y0 < H_ - 1);
        bool vx0 = (x0 >= 0)  & (x0 < W_);
        bool vx1 = (x0 >= -1) & (x0 < W_ - 1);
        float w00 = (1.f-wy)*(1.f-wx)*m*((vy0&vx0)?1.f:0.f);
        float w01 = (1.f-wy)*wx      *m*((vy0&vx1)?1.f:0.f);
        float w10 = wy*(1.f-wx)      *m*((vy1&vx0)?1.f:0.f);
        float w11 = wy*wx            *m*((vy1&vx1)?1.f:0.f);
        int y0c = min(max(y0,   0), H_-1), y1c = min(max(y0+1, 0), H_-1);
        int x0c = min(max(x0,   0), W_-1), x1c = min(max(x0+1, 0), W_-1);
        const float* p00 = xs + (size_t)(xrow + y0c*W_ + x0c)*XC_ + half*32;
        const float* p01 = xs + (size_t)(xrow + y0c*W_ + x1c)*XC_ + half*32;
        const float* p10 = xs + (size_t)(xrow + y1c*W_ + x0c)*XC_ + half*32;
        const float* p11 = xs + (size_t)(xrow + y1c*W_ + x1c)*XC_ + half*32;

        ushort_t us[32];
#pragma unroll
        for (int q = 0; q < 8; q++) {
            f4 a = *reinterpret_cast<const f4*>(p00 + q*4);
            f4 bq= *reinterpret_cast<const f4*>(p01 + q*4);
            f4 c = *reinterpret_cast<const f4*>(p10 + q*4);
            f4 d = *reinterpret_cast<const f4*>(p11 + q*4);
#pragma unroll
            for (int j = 0; j < 4; j++)
                us[q*4+j] = f2bf(w00*a[j] + w01*bq[j] + w10*c[j] + w11*d[j]);
        }

        __syncthreads();                                    // prev MFMA done
        // A tile: row pxl, 4x16B chunks, swizzled
#pragma unroll
        for (int jc = 0; jc < 4; jc++) {
            bf16x8 v8;
#pragma unroll
            for (int e = 0; e < 8; e++) v8[e] = (short)us[jc*8 + e];
            *reinterpret_cast<bf16x8*>((char*)As + pxl*128 +
                (((half*64 + jc*16) ^ ((pxl & 7) << 4)))) = v8;
        }
        // W tile: linear copy of pre-swizzled content (2 chunks/thread)
        {
            const short* wsrc = wstage + k*4096;
#pragma unroll
            for (int r = 0; r < 2; r++) {
                int ch = r*256 + t;
                bf16x8 wv8 = *reinterpret_cast<const bf16x8*>(wsrc + ch*8);
                *reinterpret_cast<bf16x8*>((char*)Ws + ch*16) = wv8;
            }
        }
        __syncthreads();                                    // drains vmem+lds

        // ---- GEMM: K=64 as 2 steps of 32 ----
#pragma unroll
        for (int s = 0; s < 2; s++) {
            const int bc = (s*64 + fq*16) ^ swz;
            bf16x8 a0 = *reinterpret_cast<const bf16x8*>((char*)As + (wv*32 +      fr)*128 + bc);
            bf16x8 a1 = *reinterpret_cast<const bf16x8*>((char*)As + (wv*32 + 16 + fr)*128 + bc);
#pragma unroll
            for (int j = 0; j < 4; j++) {
                bf16x8 bj = *reinterpret_cast<const bf16x8*>((char*)Ws + (j*16 + fr)*128 + bc);
                acc[0][j] = __builtin_amdgcn_mfma_f32_16x16x32_bf16(a0, bj, acc[0][j], 0, 0, 0);
                acc[1][j] = __builtin_amdgcn_mfma_f32_16x16x32_bf16(a1, bj, acc[1][j], 0, 0, 0);
            }
        }
    }

    // ---- epilogue: D row = wv*32 + i*16 + fq*4 + reg, col o = j*16 + fr ----
    const int bo = px0 / HW_, po = px0 % HW_;
#pragma unroll
    for (int i = 0; i < 2; i++)
#pragma unroll
        for (int j = 0; j < 4; j++) {
            int o = j*16 + fr;
            float bv = bias[o];
            f4 r = { acc[i][j][0] + bv, acc[i][j][1] + bv,
                     acc[i][j][2] + bv, acc[i][j][3] + bv };
            *reinterpret_cast<f4*>(&out[((size_t)(bo*64 + o))*HW_ + po +
                                        wv*32 + i*16 + fq*4]) = r;
        }
}

// ---------------------------------------------------------------------------
extern "C" void kernel_launch(void* const* d_in, const int* in_sizes, int n_in,
                              void* d_out, int out_size, void* d_ws, size_t ws_size,
                              hipStream_t stream)
{
    const float* x   = (const float*)d_in[0];
    const float* wt  = (const float*)d_in[1];
    const float* bs  = (const float*)d_in[2];
    const float* cmw = (const float*)d_in[3];
    const float* cmb = (const float*)d_in[4];
    float* out = (float*)d_out;

    float* xs     = (float*)d_ws;                           // NPIX_*72 f32
    float* om     = xs + (size_t)NPIX_ * XC_;               // NPIX_*28 f32
    short* wstage = (short*)(om + (size_t)NPIX_ * OMC_);    // 9*4096 bf16
    float* cwT    = (float*)(wstage + 9*4096);              // 72*9*28 f32

    prep_kernel <<<215, 256, 0, stream>>>(wt, cmw, wstage, cwT);
    xpose_kernel<<<NPIX_/128, 128, 0, stream>>>(x, xs);
    sim_kernel  <<<NPIX_/256, 256, 0, stream>>>(xs);
    cm_kernel   <<<NPIX_/256, 256, 0, stream>>>(xs, cwT, cmb, om);
    dcn_kernel  <<<NPIX_/128, 256, 0, stream>>>(xs, om, wstage, bs, out);
}